// Round 5
// baseline (321.458 us; speedup 1.0000x reference)
//
#include <hip/hip_runtime.h>

// OccupancyConnectivity on a 385^3 fp32 grid (z innermost, y stride 385,
// x stride 148225). total = sum over 3 forward axes of |a[p+off]-a[p]|.
//
// Barrier-free, LDS-free plane-marcher. Thread owns 4 CONSECUTIVE rows x 4 z
// and marches 13 planes (12 x-pairs). Per plane: 4 fresh float4 loads, one
// +4-row float4 (L1/L2 hit: it is another thread's fresh load), z-boundary
// element via __shfl_down (lane tz==31 loads it), y-diffs register-internal,
// x-diffs vs previous plane kept in registers. Logical traffic ~1.25x of
// 228 MB; HBM ~1.08x. 1152 main + 32 fixup blocks, all co-resident, no
// barriers -> maximum bytes in flight. Boundary slabs (y=384 / z=384) are
// grid-stride fixup loops (validated in R3).

constexpr int G     = 385;
constexpr int PLANE = G * G;             // 148225

#define TPB   256
#define XC    32                          // x-chunks: 12 pairs each (13 planes)
#define XP    12
#define YT    12                          // y-tiles of 32
#define ZTT   3                           // z-tiles of 128
#define FIXB  32
#define MAINB (YT * ZTT * XC)             // 1152
#define ALLB  (MAINB + FIXB)              // 1184

typedef float f4v __attribute__((ext_vector_type(4)));
typedef f4v f4u __attribute__((aligned(4)));
static __device__ __forceinline__ f4v ld4(const float* p) { return *(const f4u*)p; }

static __device__ __forceinline__ float ad(float x, float y) { return fabsf(x - y); }

__global__ __launch_bounds__(TPB) void occ_conn_main(
    const float* __restrict__ a, float* __restrict__ ws)
{
    float s = 0.f;
    const int bid = blockIdx.x;

    if (bid < FIXB) {
        // ---- boundary-slab fixups (~3.4 MB total reads) ----
        const unsigned ft = (unsigned)bid * TPB + threadIdx.x;
        const unsigned NF = FIXB * TPB;
        // F1: z-diffs on y=384: x in [0,385), z in [0,384)
        for (unsigned j = ft; j < 385u * 384u; j += NF) {
            const unsigned x = j / 384u, z = j - x * 384u;
            const unsigned p = x * (unsigned)PLANE + 384u * (unsigned)G + z;
            s += ad(a[p + 1], a[p]);
        }
        // F2: y-diffs on z=384: x in [0,385), y in [0,384)
        for (unsigned j = ft; j < 385u * 384u; j += NF) {
            const unsigned x = j / 384u, y = j - x * 384u;
            const unsigned p = x * (unsigned)PLANE + y * (unsigned)G + 384u;
            s += ad(a[p + G], a[p]);
        }
        // F3: x-diffs on y=384: x in [0,384), z in [0,385)
        for (unsigned j = ft; j < 384u * 385u; j += NF) {
            const unsigned x = j / 385u, z = j - x * 385u;
            const unsigned p = x * (unsigned)PLANE + 384u * (unsigned)G + z;
            s += ad(a[p + PLANE], a[p]);
        }
        // F4: x-diffs on z=384: x in [0,384), y in [0,384)
        for (unsigned j = ft; j < 384u * 384u; j += NF) {
            const unsigned x = j / 384u, y = j - x * 384u;
            const unsigned p = x * (unsigned)PLANE + y * (unsigned)G + 384u;
            s += ad(a[p + PLANE], a[p]);
        }
    } else {
        int t = bid - FIXB;
        const int bc = t % XC;  t /= XC;     // x-chunk
        const int by = t % YT;  t /= YT;
        const int bz = t;                    // 0..2
        const int tz = threadIdx.x & 31;     // z-chunk (4 floats)
        const int ty = threadIdx.x >> 5;     // 4-row group 0..7
        const bool lastc = (bc == XC - 1);

        const float* p0 = a + (size_t)(bc * XP) * PLANE
                            + (size_t)(by * 32 + 4 * ty) * G
                            + (size_t)(bz * 128 + 4 * tz);

        f4v pf0 = {0,0,0,0}, pf1 = {0,0,0,0}, pf2 = {0,0,0,0}, pf3 = {0,0,0,0};

        #pragma unroll 2
        for (int tt = 0; tt <= XP; ++tt) {
            const bool zy = (tt < XP) || lastc;   // z/y-diffs on this plane?

            const f4v f0 = ld4(p0);
            const f4v f1 = ld4(p0 + G);
            const f4v f2 = ld4(p0 + 2 * G);
            const f4v f3 = ld4(p0 + 3 * G);
            f4v g = {0,0,0,0};
            float h0 = 0.f, h1 = 0.f, h2 = 0.f, h3 = 0.f;
            if (zy) {
                g = ld4(p0 + 4 * G);              // row +4: another thread's f
                if (tz == 31) {                   // z-run boundary element
                    h0 = p0[4];
                    h1 = p0[G + 4];
                    h2 = p0[2 * G + 4];
                    h3 = p0[3 * G + 4];
                }
            }

            // x-diffs vs previous plane (registers)
            if (tt > 0) {
                s += ad(f0.x, pf0.x) + ad(f0.y, pf0.y) + ad(f0.z, pf0.z) + ad(f0.w, pf0.w)
                   + ad(f1.x, pf1.x) + ad(f1.y, pf1.y) + ad(f1.z, pf1.z) + ad(f1.w, pf1.w)
                   + ad(f2.x, pf2.x) + ad(f2.y, pf2.y) + ad(f2.z, pf2.z) + ad(f2.w, pf2.w)
                   + ad(f3.x, pf3.x) + ad(f3.y, pf3.y) + ad(f3.z, pf3.z) + ad(f3.w, pf3.w);
            }

            if (zy) {
                // z-run boundary via intra-wave shuffle (lane tz+1's f.x)
                float n0 = __shfl_down(f0.x, 1);
                float n1 = __shfl_down(f1.x, 1);
                float n2 = __shfl_down(f2.x, 1);
                float n3 = __shfl_down(f3.x, 1);
                if (tz == 31) { n0 = h0; n1 = h1; n2 = h2; n3 = h3; }

                // z-diffs (4 per row)
                s += ad(f0.y, f0.x) + ad(f0.z, f0.y) + ad(f0.w, f0.z) + ad(n0, f0.w)
                   + ad(f1.y, f1.x) + ad(f1.z, f1.y) + ad(f1.w, f1.z) + ad(n1, f1.w)
                   + ad(f2.y, f2.x) + ad(f2.z, f2.y) + ad(f2.w, f2.z) + ad(n2, f2.w)
                   + ad(f3.y, f3.x) + ad(f3.z, f3.y) + ad(f3.w, f3.z) + ad(n3, f3.w);
                // y-diffs (3 internal + 1 vs row+4)
                s += ad(f1.x, f0.x) + ad(f1.y, f0.y) + ad(f1.z, f0.z) + ad(f1.w, f0.w)
                   + ad(f2.x, f1.x) + ad(f2.y, f1.y) + ad(f2.z, f1.z) + ad(f2.w, f1.w)
                   + ad(f3.x, f2.x) + ad(f3.y, f2.y) + ad(f3.z, f2.z) + ad(f3.w, f2.w)
                   + ad(g.x,  f3.x) + ad(g.y,  f3.y) + ad(g.z,  f3.z) + ad(g.w,  f3.w);
            }

            pf0 = f0; pf1 = f1; pf2 = f2; pf3 = f3;
            p0 += PLANE;
        }
    }

    // ---- block reduction ----
    #pragma unroll
    for (int off = 32; off > 0; off >>= 1) s += __shfl_down(s, off, 64);
    __shared__ float ls[TPB / 64];
    const int lane = threadIdx.x & 63;
    const int wid  = threadIdx.x >> 6;
    if (lane == 0) ls[wid] = s;
    __syncthreads();
    if (threadIdx.x == 0) {
        float tsum = 0.f;
        #pragma unroll
        for (int w = 0; w < TPB / 64; ++w) tsum += ls[w];
        ws[blockIdx.x] = tsum;
    }
}

__global__ __launch_bounds__(256) void occ_conn_final(
    const float* __restrict__ ws, float* __restrict__ out)
{
    float s = 0.f;
    for (int i = threadIdx.x; i < ALLB; i += 256) s += ws[i];
    #pragma unroll
    for (int off = 32; off > 0; off >>= 1) s += __shfl_down(s, off, 64);
    __shared__ float ls[4];
    const int lane = threadIdx.x & 63;
    const int wid  = threadIdx.x >> 6;
    if (lane == 0) ls[wid] = s;
    __syncthreads();
    if (threadIdx.x == 0) out[0] = ls[0] + ls[1] + ls[2] + ls[3];
}

extern "C" void kernel_launch(void* const* d_in, const int* in_sizes, int n_in,
                              void* d_out, int out_size, void* d_ws, size_t ws_size,
                              hipStream_t stream)
{
    const float* a   = (const float*)d_in[0];
    float*       out = (float*)d_out;
    float*       ws  = (float*)d_ws;   // ALLB floats; fully overwritten each call

    occ_conn_main<<<ALLB, TPB, 0, stream>>>(a, ws);
    occ_conn_final<<<1, 256, 0, stream>>>(ws, out);
}